// Round 7
// baseline (117125.647 us; speedup 1.0000x reference)
//
#include <hip/hip_runtime.h>
#include <math.h>

#define TN 1024
#define HH 512
#define BB 256
#define NTHR 1024
#define NBLK 256

#define OFF_KEYS 0L
#define OFF_PRS  524288L
#define OFF_HS   1572864L
#define OFF_TM   135790592L

// d_ws layout (bytes)
#define WHF_OFF  0L          // 512 KB fp16 weights
#define SEQ_OFF  524288L     // 256 uint flags
#define XBUF_OFF 528384L     // exchange: [16 m][2 par][16 n] x 320 dw
#define XSTRIDE  320

typedef float f32x4 __attribute__((ext_vector_type(4)));
typedef _Float16 f16x2 __attribute__((ext_vector_type(2)));

__device__ __forceinline__ float sigm(float x) { return 1.0f / (1.0f + expf(-x)); }

__device__ __forceinline__ float dot2(unsigned a, unsigned b, float c) {
#if __has_builtin(__builtin_amdgcn_fdot2)
    return __builtin_amdgcn_fdot2(__builtin_bit_cast(f16x2, a),
                                  __builtin_bit_cast(f16x2, b), c, false);
#else
    const f16x2 x = __builtin_bit_cast(f16x2, a);
    const f16x2 y = __builtin_bit_cast(f16x2, b);
    return fmaf((float)x.y, (float)y.y, fmaf((float)x.x, (float)y.x, c));
#endif
}

// ---- pre-kernel: w_rec f32 -> fp16 in d_ws; zero seq flags ----
__global__ __launch_bounds__(256) void conv_fp16(const float* __restrict__ w,
                                                 char* __restrict__ ws) {
    _Float16* o = (_Float16*)(ws + WHF_OFF);
    const int i = (blockIdx.x * 256 + threadIdx.x) * 4;
    const f32x4 v = *(const f32x4*)(w + i);
    _Float16 r[4];
    #pragma unroll
    for (int k = 0; k < 4; ++k) r[k] = (_Float16)v[k];
    *(unsigned long long*)(o + i) = *(const unsigned long long*)r;
    if (blockIdx.x == 0) ((unsigned*)(ws + SEQ_OFF))[threadIdx.x] = 0u;
}

__global__ __launch_bounds__(NTHR, 4) void rnn_fused(
    const float* __restrict__ in, const float* __restrict__ w_in,
    const float* __restrict__ b_in, const float* __restrict__ b_rec,
    const float* __restrict__ w_key, const float* __restrict__ b_key,
    const float* __restrict__ z, float* __restrict__ out,
    char* __restrict__ ws)
{
    __shared__ unsigned wlds[16][320];          // 20 KB: rows rg*8+{4..7}, ks-padded
    __shared__ unsigned hbuf[2][16][320];       // 40 KB: h fp16, ks-padded (stride 20 dw)
    __shared__ float tbuf[2][16][32][17];       // 68 KB: hs 16-step tiles
    __shared__ unsigned hstage[256];            // 1 KB: own slice h for publish
    __shared__ float kpart[16][16][2];          // 2 KB: key partials [slice][batch]
    __shared__ float keysT[2][16][2][16];
    __shared__ float prsT[2][16][4][16];
    __shared__ float tmT[2][16][16];
    __shared__ float bsum_s[32];
    __shared__ float wi_s[32][6];
    __shared__ float wk_s[2][32];

    const int tid = threadIdx.x;
    const int m = blockIdx.x & 15, n = blockIdx.x >> 4;
    const int wv = tid >> 6, ln = tid & 63;
    const int rg = ln >> 4, ks = ln & 15;
    const int bi = m * 16 + wv;                  // this wave's batch
    const float* inb = in + (long)bi * 8 * TN;

    const unsigned* whf = (const unsigned*)(ws + WHF_OFF);   // [512 rows][256 dw]
    unsigned* seq  = (unsigned*)(ws + SEQ_OFF);
    unsigned* xbuf = (unsigned*)(ws + XBUF_OFF);

    // ---------------- init ----------------
    uint4 wreg[16];                              // rows n*32+rg*8+{0..3}, 32 fp16 each
    #pragma unroll
    for (int r = 0; r < 4; ++r) {
        const unsigned* src = whf + ((n * 32 + rg * 8 + r) * 256 + ks * 16);
        #pragma unroll
        for (int c = 0; c < 4; ++c) wreg[r * 4 + c] = *(const uint4*)(src + c * 4);
    }
    for (int idx = tid; idx < 4096; idx += NTHR) {           // wlds rows {4..7} of each group
        int lrow = idx >> 8, dd = idx & 255;
        int j = n * 32 + (lrow >> 2) * 8 + 4 + (lrow & 3);
        wlds[lrow][(dd >> 4) * 20 + (dd & 15)] = whf[j * 256 + dd];
    }
    for (int idx = tid; idx < 16 * 320; idx += NTHR) hbuf[0][idx / 320][idx % 320] = 0u;
    if (tid < 512) tbuf[0][tid >> 5][tid & 31][0] = 0.0f;
    if (tid < 16) {
        keysT[0][tid][0][0] = 0.f; keysT[0][tid][1][0] = 0.f;
        prsT[0][tid][0][0] = 0.f; prsT[0][tid][1][0] = 0.f;
        prsT[0][tid][2][0] = 0.f; prsT[0][tid][3][0] = 0.f;
        tmT[0][tid][0] = in[((long)(m * 16 + tid)) * 8 * TN + 7 * TN];
    }
    if (tid < 32) {
        int j = n * 32 + tid;
        bsum_s[tid] = b_in[j] + b_rec[j];
        wk_s[0][tid] = w_key[j]; wk_s[1][tid] = w_key[HH + j];
        #pragma unroll
        for (int c = 0; c < 6; ++c) wi_s[tid][c] = w_in[j * 6 + c];
    }
    if (n == 0) {                                 // tm_modified[:,0,:] = tm1
        for (int rep = 0; rep < 4; ++rep) {
            int item = rep * NTHR + tid;          // 0..4095
            int b = item >> 8, c = item & 255;
            f32x4 v = *(const f32x4*)(in + ((long)(m * 16 + b)) * 8 * TN + 6 * TN + c * 4);
            __builtin_nontemporal_store(v,
                (f32x4*)(out + OFF_TM + ((long)(m * 16 + b)) * 2 * TN + c * 4));
        }
    }
    int idxm;                                     // argmax(tm1) first-occurrence, per wave
    {
        const float* tp = inb + 6 * TN;
        float bv = -3.0e38f; int bix = 0;
        for (int i = 0; i < 16; ++i) { int tt = i * 64 + ln; float v = tp[tt]; if (v > bv) { bv = v; bix = tt; } }
        #pragma unroll
        for (int mk = 1; mk < 64; mk <<= 1) {
            float ov = __shfl_xor(bv, mk); int oi = __shfl_xor(bix, mk);
            if (ov > bv || (ov == bv && oi < bix)) { bv = ov; bix = oi; }
        }
        idxm = bix;
    }
    float kh = 1.0f, off = 0.0f; int side_pre = 1;           // lane-0 stage carries
    float q0=0,q1=0,q2=0,q3=0,q4=0,q5=0,q6=0,q7=0,qz=0;      // prefetched stage inputs
    const float bk0 = b_key[0], bk1 = b_key[1];
    if (ln == 0) {
        q0=inb[1]; q1=inb[TN+1]; q2=inb[2*TN+1]; q3=inb[3*TN+1];
        q4=inb[4*TN+1]; q5=inb[5*TN+1]; q6=inb[6*TN+1]; q7=inb[7*TN+1];
        qz=z[bi];
    }
    __syncthreads();

    auto do_flush = [&](int ft, int t0) {
        if (wv >= 8) {                            // hs tile
            const int b = (wv - 8) * 2 + (ln >> 5), srow = ln & 31;
            const float* tr = &tbuf[ft][b][srow][0];
            float* dst = out + OFF_HS + (((long)(m * 16 + b)) * HH + n * 32 + srow) * TN + t0;
            #pragma unroll
            for (int c = 0; c < 4; ++c) {
                f32x4 v; v.x = tr[c*4]; v.y = tr[c*4+1]; v.z = tr[c*4+2]; v.w = tr[c*4+3];
                __builtin_nontemporal_store(v, (f32x4*)(dst + c * 4));
            }
        }
        if (wv == 0 && n == 0) {                  // keys/prs/tm tiles
            #pragma unroll
            for (int rep = 0; rep < 7; ++rep) {
                int item = rep * 64 + ln;
                if (item < 128) {
                    int b = item >> 3, ch = (item >> 2) & 1, c4 = item & 3;
                    __builtin_nontemporal_store(*(const f32x4*)&keysT[ft][b][ch][c4 * 4],
                        (f32x4*)(out + OFF_KEYS + ((long)(m * 16 + b)) * 2 * TN + ch * TN + t0 + c4 * 4));
                } else if (item < 384) {
                    int i2 = item - 128, b = i2 >> 4, ch = (i2 >> 2) & 3, c4 = i2 & 3;
                    __builtin_nontemporal_store(*(const f32x4*)&prsT[ft][b][ch][c4 * 4],
                        (f32x4*)(out + OFF_PRS + ((long)(m * 16 + b)) * 4 * TN + ch * TN + t0 + c4 * 4));
                } else {
                    int i3 = item - 384, b = i3 >> 2, c4 = i3 & 3;
                    __builtin_nontemporal_store(*(const f32x4*)&tmT[ft][b][c4 * 4],
                        (f32x4*)(out + OFF_TM + ((long)(m * 16 + b)) * 2 * TN + TN + t0 + c4 * 4));
                }
            }
        }
    };

    // ---------------- time loop ----------------
    for (int t = 1; t < TN; ++t) {
        const int par1 = (t - 1) & 1, par2 = t & 1;
        const int tile = (t >> 4) & 1, sl = t & 15;

        // ---- key(t-1) deterministic butterfly + stage(t) on lane 0 ----
        float i0 = 0, i1 = 0, i2 = 0, i3 = 0, i4 = 0, i5 = 0;
        if (t > 1) {
            float kv0 = (ln < 16) ? kpart[ln][wv][0] : 0.f;
            float kv1 = (ln < 16) ? kpart[ln][wv][1] : 0.f;
            #pragma unroll
            for (int mk = 1; mk < 16; mk <<= 1) { kv0 += __shfl_xor(kv0, mk, 16); kv1 += __shfl_xor(kv1, mk, 16); }
            if (ln == 0) {
                const float key0 = sigm(kv0 + bk0), key1 = sigm(kv1 + bk1);
                const int pt = t - 1;
                keysT[(pt >> 4) & 1][wv][0][pt & 15] = key0;
                keysT[(pt >> 4) & 1][wv][1][pt & 15] = key1;
                kh = key0;
            }
        }
        if (ln == 0) {
            const int side = (kh > 0.5f);
            const float as0 = q2 * kh + q4 * (1.0f - kh);
            const float as1 = q3 * kh + q5 * (1.0f - kh);
            const int closer1 = (fabsf(q0 - q6) <= fabsf(q1 - q6));
            const int done = (t > idxm);
            const int sw = ((side != side_pre) && done && (side != closer1));
            const float t2c = q7 + off;
            if (sw) off += qz * fabsf(0.05f * t2c);
            const float t2e = q7 + off;
            side_pre = side;
            float u0 = (q6 - q0) / (0.15f * q0);   float pr10 = (q6 == 0.f) ? 0.f : u0 * u0;
            float u1 = (q6 - q1) / (0.15f * q1);   float pr11 = (q6 == 0.f) ? 0.f : u1 * u1;
            float u2 = (t2e - as0) / (0.15f * as0); float pr20 = (t2e == 0.f) ? 0.f : u2 * u2;
            float u3 = (t2e - as1) / (0.15f * as1); float pr21 = (t2e == 0.f) ? 0.f : u3 * u3;
            prsT[tile][wv][0][sl] = pr10; prsT[tile][wv][1][sl] = pr11;
            prsT[tile][wv][2][sl] = pr20; prsT[tile][wv][3][sl] = pr21;
            tmT[tile][wv][sl] = t2e;
            i0 = q0; i1 = q1; i2 = as0; i3 = as1; i4 = q6; i5 = t2e;
            const int tn = (t < TN - 1) ? t + 1 : t;           // clamped prefetch
            q0 = inb[tn]; q1 = inb[TN + tn]; q2 = inb[2 * TN + tn]; q3 = inb[3 * TN + tn];
            q4 = inb[4 * TN + tn]; q5 = inb[5 * TN + tn]; q6 = inb[6 * TN + tn]; q7 = inb[7 * TN + tn];
            qz = z[(long)(tn - 1) * BB + bi];
        }
        i0 = __shfl(i0, 0); i1 = __shfl(i1, 0); i2 = __shfl(i2, 0);
        i3 = __shfl(i3, 0); i4 = __shfl(i4, 0); i5 = __shfl(i5, 0);

        // ---- GEMV: 8 rows (4 reg + 4 LDS), 16-lane K-split ----
        float acc[8] = {0, 0, 0, 0, 0, 0, 0, 0};
        {
            const unsigned* hb = &hbuf[par1][wv][ks * 20];
            #pragma unroll
            for (int c = 0; c < 4; ++c) {
                const uint4 hu = *(const uint4*)(hb + c * 4);
                #pragma unroll
                for (int r = 0; r < 4; ++r) {
                    const uint4 wu = wreg[r * 4 + c];
                    acc[r] = dot2(wu.x, hu.x, acc[r]); acc[r] = dot2(wu.y, hu.y, acc[r]);
                    acc[r] = dot2(wu.z, hu.z, acc[r]); acc[r] = dot2(wu.w, hu.w, acc[r]);
                }
                #pragma unroll
                for (int rr = 0; rr < 4; ++rr) {
                    const uint4 wu = *(const uint4*)(&wlds[rg * 4 + rr][ks * 20 + c * 4]);
                    acc[4 + rr] = dot2(wu.x, hu.x, acc[4 + rr]); acc[4 + rr] = dot2(wu.y, hu.y, acc[4 + rr]);
                    acc[4 + rr] = dot2(wu.z, hu.z, acc[4 + rr]); acc[4 + rr] = dot2(wu.w, hu.w, acc[4 + rr]);
                }
            }
        }
        // distributing reduce (no runtime reg indexing): lane ks ends with row rg*8+(ks&7)
        float srow_sum;
        {
            const bool s1 = ks & 1, s2 = ks & 2, s3 = ks & 4;
            float a01 = s1 ? acc[1] : acc[0], b01 = s1 ? acc[0] : acc[1];
            float a23 = s1 ? acc[3] : acc[2], b23 = s1 ? acc[2] : acc[3];
            float a45 = s1 ? acc[5] : acc[4], b45 = s1 ? acc[4] : acc[5];
            float a67 = s1 ? acc[7] : acc[6], b67 = s1 ? acc[6] : acc[7];
            a01 += __shfl_xor(b01, 1, 16); a23 += __shfl_xor(b23, 1, 16);
            a45 += __shfl_xor(b45, 1, 16); a67 += __shfl_xor(b67, 1, 16);
            float c03 = s2 ? a23 : a01, d03 = s2 ? a01 : a23;
            float c47 = s2 ? a67 : a45, d47 = s2 ? a45 : a67;
            c03 += __shfl_xor(d03, 2, 16); c47 += __shfl_xor(d47, 2, 16);
            float e = s3 ? c47 : c03, f = s3 ? c03 : c47;
            e += __shfl_xor(f, 4, 16);
            srow_sum = e + __shfl_xor(e, 8, 16);
        }
        // ---- finalize (writer lanes ks<8) ----
        float ka0 = 0.f, ka1 = 0.f;
        if (ks < 8) {
            const int srow = rg * 8 + ks;
            float s = srow_sum + bsum_s[srow]
                    + wi_s[srow][0] * i0 + wi_s[srow][1] * i1 + wi_s[srow][2] * i2
                    + wi_s[srow][3] * i3 + wi_s[srow][4] * i4 + wi_s[srow][5] * i5;
            const float hv = tanhf(s);
            tbuf[tile][wv][srow][sl] = hv;
            const _Float16 hf = (_Float16)hv;
            ((_Float16*)&hbuf[par2][wv][0])[n * 40 + srow] = hf;
            ((_Float16*)hstage)[wv * 32 + srow] = hf;
            ka0 = hv * wk_s[0][srow]; ka1 = hv * wk_s[1][srow];
        }
        #pragma unroll
        for (int mk = 1; mk < 64; mk <<= 1) { ka0 += __shfl_xor(ka0, mk); ka1 += __shfl_xor(ka1, mk); }
        if (ln == 0) { kpart[n][wv][0] = ka0; kpart[n][wv][1] = ka1; }
        __syncthreads();                           // A

        // ---- phase 2: publish / import / flush ----
        if (wv == 0) {
            unsigned* dst = xbuf + ((m * 2 + par2) * 16 + n) * XSTRIDE;
            const uint4 hv4 = *(const uint4*)(hstage + ln * 4);
            __hip_atomic_store(dst + ln * 4 + 0, hv4.x, __ATOMIC_RELAXED, __HIP_MEMORY_SCOPE_AGENT);
            __hip_atomic_store(dst + ln * 4 + 1, hv4.y, __ATOMIC_RELAXED, __HIP_MEMORY_SCOPE_AGENT);
            __hip_atomic_store(dst + ln * 4 + 2, hv4.z, __ATOMIC_RELAXED, __HIP_MEMORY_SCOPE_AGENT);
            __hip_atomic_store(dst + ln * 4 + 3, hv4.w, __ATOMIC_RELAXED, __HIP_MEMORY_SCOPE_AGENT);
            if (ln < 32)
                __hip_atomic_store(dst + 256 + ln, __float_as_uint(kpart[n][ln >> 1][ln & 1]),
                                   __ATOMIC_RELAXED, __HIP_MEMORY_SCOPE_AGENT);
            if (ln == 0)
                __hip_atomic_store(seq + (m * 16 + n), (unsigned)t,
                                   __ATOMIC_RELEASE, __HIP_MEMORY_SCOPE_AGENT);
        } else {
            const int np = (n + wv) & 15;
            if (ln == 0) {
                while (__hip_atomic_load(seq + (m * 16 + np), __ATOMIC_ACQUIRE,
                                         __HIP_MEMORY_SCOPE_AGENT) < (unsigned)t)
                    __builtin_amdgcn_s_sleep(1);
            }
            __builtin_amdgcn_sched_barrier(0);
            const unsigned* src = xbuf + ((m * 2 + par2) * 16 + np) * XSTRIDE;
            const unsigned v0 = __hip_atomic_load(src + ln * 4 + 0, __ATOMIC_RELAXED, __HIP_MEMORY_SCOPE_AGENT);
            const unsigned v1 = __hip_atomic_load(src + ln * 4 + 1, __ATOMIC_RELAXED, __HIP_MEMORY_SCOPE_AGENT);
            const unsigned v2 = __hip_atomic_load(src + ln * 4 + 2, __ATOMIC_RELAXED, __HIP_MEMORY_SCOPE_AGENT);
            const unsigned v3 = __hip_atomic_load(src + ln * 4 + 3, __ATOMIC_RELAXED, __HIP_MEMORY_SCOPE_AGENT);
            const int b2 = ln >> 2, dd0 = (ln << 2) & 15;
            unsigned* dh = &hbuf[par2][b2][np * 20 + dd0];
            dh[0] = v0; dh[1] = v1; dh[2] = v2; dh[3] = v3;
            if (ln < 32)
                kpart[np][ln >> 1][ln & 1] = __uint_as_float(
                    __hip_atomic_load(src + 256 + ln, __ATOMIC_RELAXED, __HIP_MEMORY_SCOPE_AGENT));
        }
        if (sl == 0) do_flush(tile ^ 1, t - 16);
        __syncthreads();                           // B
    }

    // ---------------- epilogue: key(1023) + final tile ----------------
    {
        float kv0 = (ln < 16) ? kpart[ln][wv][0] : 0.f;
        float kv1 = (ln < 16) ? kpart[ln][wv][1] : 0.f;
        #pragma unroll
        for (int mk = 1; mk < 16; mk <<= 1) { kv0 += __shfl_xor(kv0, mk, 16); kv1 += __shfl_xor(kv1, mk, 16); }
        if (ln == 0) {
            keysT[1][wv][0][15] = sigm(kv0 + bk0);
            keysT[1][wv][1][15] = sigm(kv1 + bk1);
        }
    }
    __syncthreads();
    do_flush(1, TN - 16);
}

extern "C" void kernel_launch(void* const* d_in, const int* in_sizes, int n_in,
                              void* d_out, int out_size, void* d_ws, size_t ws_size,
                              hipStream_t stream) {
    (void)in_sizes; (void)n_in; (void)out_size; (void)ws_size;
    const float* in    = (const float*)d_in[0];
    const float* w_in  = (const float*)d_in[1];
    const float* b_in  = (const float*)d_in[2];
    const float* w_rec = (const float*)d_in[3];
    const float* b_rec = (const float*)d_in[4];
    const float* w_key = (const float*)d_in[5];
    const float* b_key = (const float*)d_in[6];
    const float* z     = (const float*)d_in[7];
    float* out = (float*)d_out;
    char* ws = (char*)d_ws;

    hipLaunchKernelGGL(conv_fp16, dim3(HH * HH / 1024), dim3(256), 0, stream, w_rec, ws);
    hipLaunchKernelGGL(rnn_fused, dim3(NBLK), dim3(NTHR), 0, stream,
                       in, w_in, b_in, b_rec, w_key, b_key, z, out, ws);
}

// Round 8
// 3787.376 us; speedup vs baseline: 30.9253x; 30.9253x over previous
//
#include <hip/hip_runtime.h>
#include <math.h>

#define TN 1024
#define HH 512
#define BB 256
#define NTHR 512
#define NW48 48              // uint4 per thread in registers (K 0..383)
#define TSTRIDE 136          // fp16 stride of wtail row (272 B = 17*16B)

#define OFF_KEYS 0L
#define OFF_PRS  524288L
#define OFF_HS   1572864L
#define OFF_TM   135790592L

typedef float f32x4 __attribute__((ext_vector_type(4)));
typedef _Float16 f16x2 __attribute__((ext_vector_type(2)));

__device__ __forceinline__ float sigm(float x) { return 1.0f / (1.0f + expf(-x)); }

__device__ __forceinline__ float dot2(unsigned a, unsigned b, float c) {
#if __has_builtin(__builtin_amdgcn_fdot2)
    return __builtin_amdgcn_fdot2(__builtin_bit_cast(f16x2, a),
                                  __builtin_bit_cast(f16x2, b), c, false);
#else
    const f16x2 x = __builtin_bit_cast(f16x2, a);
    const f16x2 y = __builtin_bit_cast(f16x2, b);
    return fmaf((float)x.y, (float)y.y, fmaf((float)x.x, (float)y.x, c));
#endif
}

// ---- pre-kernel: w_rec f32 -> fp16 row-major in d_ws ----
__global__ __launch_bounds__(256) void conv_fp16(const float* __restrict__ w,
                                                 _Float16* __restrict__ o) {
    const int i = (blockIdx.x * 256 + threadIdx.x) * 4;
    const f32x4 v = *(const f32x4*)(w + i);
    _Float16 r[4];
    #pragma unroll
    for (int k = 0; k < 4; ++k) r[k] = (_Float16)v[k];
    *(unsigned long long*)(o + i) = *(const unsigned long long*)r;
}

__global__ __launch_bounds__(NTHR, 2) void rnn_fused(
    const float* __restrict__ in, const float* __restrict__ w_in,
    const float* __restrict__ b_in, const float* __restrict__ b_rec,
    const float* __restrict__ w_key, const float* __restrict__ b_key,
    const float* __restrict__ z, float* __restrict__ out,
    const _Float16* __restrict__ whf)
{
    __shared__ __align__(16) _Float16 wtail[HH][TSTRIDE];  // 139,264 B: K 384..511
    __shared__ __align__(16) float tbuf[HH][9];            // 18,432 B: hs 8-step tile
    __shared__ __align__(16) _Float16 hsh[2][HH];          // 2 KB
    __shared__ float keysT[2][2][16];
    __shared__ float prsT[2][4][16];
    __shared__ float tmT[2][16];
    __shared__ float inp6[8];
    __shared__ float kred[8][2];

    const int tid = threadIdx.x;
    const int bb  = blockIdx.x;                 // one batch per block
    const int wv  = tid >> 6, ln = tid & 63;
    const float* inb = in + (long)bb * 8 * TN;
    const unsigned* wrow = (const unsigned*)(whf + (long)tid * HH);   // 256 dw

    // ---- weights: K 0..383 into registers (statically indexed) ----
    uint4 wreg[NW48];
    #pragma unroll
    for (int i = 0; i < NW48; ++i) wreg[i] = *(const uint4*)(wrow + i * 4);
    // ---- weights: K 384..511 into LDS (own row) ----
    {
        const uint4* src = (const uint4*)(wrow + 192);       // dw 192..255
        #pragma unroll
        for (int i = 0; i < 16; ++i) *(uint4*)&wtail[tid][i * 8] = src[i];
    }

    // ---- per-lane row constants ----
    const float bs  = b_in[tid] + b_rec[tid];
    const float wk0 = w_key[tid], wk1 = w_key[HH + tid];
    const float* wip = w_in + tid * 6;
    const float wi0 = wip[0], wi1 = wip[1], wi2 = wip[2];
    const float wi3 = wip[3], wi4 = wip[4], wi5 = wip[5];

    // ---- init LDS state ----
    hsh[0][tid] = (_Float16)0.0f;
    tbuf[tid][0] = 0.0f;
    if (tid < 256) {    // tm_modified[bb,0,:] = tm1
        f32x4 v = *(const f32x4*)(inb + 6 * TN + tid * 4);
        __builtin_nontemporal_store(v, (f32x4*)(out + OFF_TM + (long)bb * 2 * TN + tid * 4));
    }
    if (tid == 0) {
        keysT[0][0][0] = 0.f; keysT[0][1][0] = 0.f;
        prsT[0][0][0] = 0.f; prsT[0][1][0] = 0.f;
        prsT[0][2][0] = 0.f; prsT[0][3][0] = 0.f;
        tmT[0][0] = inb[7 * TN];          // tm2[:,0]
    }
    // argmax(tm1) first-occurrence — wave 0
    int idxm = 0;
    if (wv == 0) {
        const float* tp = inb + 6 * TN;
        float bv = -3.0e38f; int bi = 0;
        for (int i = 0; i < 16; ++i) { int tt = i * 64 + ln; float v = tp[tt]; if (v > bv) { bv = v; bi = tt; } }
        #pragma unroll
        for (int m = 1; m < 64; m <<= 1) {
            float ov = __shfl_xor(bv, m); int oi = __shfl_xor(bi, m);
            if (ov > bv || (ov == bv && oi < bi)) { bv = ov; bi = oi; }
        }
        idxm = bi;
    }
    float kh = 1.0f, off = 0.0f; int side_pre = 1;       // lane-0 carries
    float q0=0,q1=0,q2=0,q3=0,q4=0,q5=0,q6=0,q7=0,qz=0;
    const float bk0 = b_key[0], bk1 = b_key[1];
    if (tid == 0) {
        q0=inb[1]; q1=inb[TN+1]; q2=inb[2*TN+1]; q3=inb[3*TN+1];
        q4=inb[4*TN+1]; q5=inb[5*TN+1]; q6=inb[6*TN+1]; q7=inb[7*TN+1];
        qz=z[bb];
    }
    __syncthreads();

    // ---------------- time loop ----------------
    for (int t = 1; t < TN; ++t) {
        const int par1 = (t - 1) & 1, par2 = t & 1;
        const int tile = (t >> 4) & 1, sl = t & 15;

        // ---- stage on thread 0 (runs concurrent with other waves' GEMV) ----
        if (tid == 0) {
            if (t > 1) {
                float k0 = 0.f, k1 = 0.f;
                #pragma unroll
                for (int w = 0; w < 8; ++w) { k0 += kred[w][0]; k1 += kred[w][1]; }
                const float key0 = sigm(k0 + bk0), key1 = sigm(k1 + bk1);
                const int pt = t - 1;
                keysT[(pt >> 4) & 1][0][pt & 15] = key0;
                keysT[(pt >> 4) & 1][1][pt & 15] = key1;
                kh = key0;
            }
            const int side = (kh > 0.5f);
            const float as0 = q2 * kh + q4 * (1.0f - kh);
            const float as1 = q3 * kh + q5 * (1.0f - kh);
            const int closer1 = (fabsf(q0 - q6) <= fabsf(q1 - q6));
            const int done = (t > idxm);
            const int sw = ((side != side_pre) && done && (side != closer1));
            const float t2c = q7 + off;
            if (sw) off += qz * fabsf(0.05f * t2c);
            const float t2e = q7 + off;
            side_pre = side;
            float u0 = (q6 - q0) / (0.15f * q0);    float pr10 = (q6 == 0.f) ? 0.f : u0 * u0;
            float u1 = (q6 - q1) / (0.15f * q1);    float pr11 = (q6 == 0.f) ? 0.f : u1 * u1;
            float u2 = (t2e - as0) / (0.15f * as0); float pr20 = (t2e == 0.f) ? 0.f : u2 * u2;
            float u3 = (t2e - as1) / (0.15f * as1); float pr21 = (t2e == 0.f) ? 0.f : u3 * u3;
            prsT[tile][0][sl] = pr10; prsT[tile][1][sl] = pr11;
            prsT[tile][2][sl] = pr20; prsT[tile][3][sl] = pr21;
            tmT[tile][sl] = t2e;
            inp6[0] = q0; inp6[1] = q1; inp6[2] = as0;
            inp6[3] = as1; inp6[4] = q6; inp6[5] = t2e;
            const int tn = (t < TN - 1) ? t + 1 : t;            // clamped prefetch
            q0 = inb[tn]; q1 = inb[TN + tn]; q2 = inb[2 * TN + tn]; q3 = inb[3 * TN + tn];
            q4 = inb[4 * TN + tn]; q5 = inb[5 * TN + tn]; q6 = inb[6 * TN + tn]; q7 = inb[7 * TN + tn];
            qz = z[(long)(tn - 1) * BB + bb];
        }

        // ---- GEMV: full row tid, 256 dot2 (192 reg-weights + 64 LDS-tail) ----
        float a0 = 0.f, a1 = 0.f, a2 = 0.f, a3 = 0.f;
        const unsigned* hb = (const unsigned*)&hsh[par1][0];     // 256 dw, wave-uniform
        #pragma unroll
        for (int i = 0; i < NW48; ++i) {
            const uint4 hu = *(const uint4*)(hb + i * 4);
            a0 = dot2(wreg[i].x, hu.x, a0);
            a1 = dot2(wreg[i].y, hu.y, a1);
            a2 = dot2(wreg[i].z, hu.z, a2);
            a3 = dot2(wreg[i].w, hu.w, a3);
        }
        #pragma unroll
        for (int i = 0; i < 16; ++i) {
            const uint4 hu = *(const uint4*)(hb + 192 + i * 4);
            const uint4 wu = *(const uint4*)&wtail[tid][i * 8];
            a0 = dot2(wu.x, hu.x, a0);
            a1 = dot2(wu.y, hu.y, a1);
            a2 = dot2(wu.z, hu.z, a2);
            a3 = dot2(wu.w, hu.w, a3);
        }
        const float sdot = (a0 + a1) + (a2 + a3);
        __syncthreads();    // A: h reads done; inp6/prsT/tmT visible

        // ---- finalize row tid ----
        {
            const float s = sdot + bs
                          + wi0 * inp6[0] + wi1 * inp6[1] + wi2 * inp6[2]
                          + wi3 * inp6[3] + wi4 * inp6[4] + wi5 * inp6[5];
            const float h = tanhf(s);
            hsh[par2][tid] = (_Float16)h;
            tbuf[tid][t & 7] = h;
            float ka0 = h * wk0, ka1 = h * wk1;
            #pragma unroll
            for (int m = 1; m < 64; m <<= 1) { ka0 += __shfl_xor(ka0, m); ka1 += __shfl_xor(ka1, m); }
            if (ln == 0) { kred[wv][0] = ka0; kred[wv][1] = ka1; }
        }
        __syncthreads();    // D: hsh/kred/tbuf visible

        // ---- hs flush every 8 steps: each thread flushes ITS OWN row ----
        if ((t & 7) == 7) {
            const int t0 = t - 7;
            const float* tr = &tbuf[tid][0];
            f32x4 v0, v1;
            v0.x = tr[0]; v0.y = tr[1]; v0.z = tr[2]; v0.w = tr[3];
            v1.x = tr[4]; v1.y = tr[5]; v1.z = tr[6]; v1.w = tr[7];
            float* dst = out + OFF_HS + ((long)bb * HH + tid) * TN + t0;
            __builtin_nontemporal_store(v0, (f32x4*)dst);
            __builtin_nontemporal_store(v1, (f32x4*)(dst + 4));
        }
        // ---- keys/prs/tm flush every 16 steps (wave 0) ----
        if ((t & 15) == 0 && wv == 0) {
            const int f = tile ^ 1, t0 = t - 16;
            if (ln < 8) {
                const int ch = ln >> 2, c4 = ln & 3;
                __builtin_nontemporal_store(*(const f32x4*)&keysT[f][ch][c4 * 4],
                    (f32x4*)(out + OFF_KEYS + (long)bb * 2 * TN + ch * TN + t0 + c4 * 4));
            } else if (ln < 24) {
                const int ix = ln - 8, ch = ix >> 2, c4 = ix & 3;
                __builtin_nontemporal_store(*(const f32x4*)&prsT[f][ch][c4 * 4],
                    (f32x4*)(out + OFF_PRS + (long)bb * 4 * TN + ch * TN + t0 + c4 * 4));
            } else if (ln < 28) {
                const int c4 = ln - 24;
                __builtin_nontemporal_store(*(const f32x4*)&tmT[f][c4 * 4],
                    (f32x4*)(out + OFF_TM + (long)bb * 2 * TN + TN + t0 + c4 * 4));
            }
        }
    }

    // ---------------- epilogue: key(1023) + final keys/prs/tm tile ----------------
    if (tid == 0) {
        float k0 = 0.f, k1 = 0.f;
        #pragma unroll
        for (int w = 0; w < 8; ++w) { k0 += kred[w][0]; k1 += kred[w][1]; }
        keysT[1][0][15] = sigm(k0 + bk0);
        keysT[1][1][15] = sigm(k1 + bk1);
    }
    __syncthreads();
    if (wv == 0) {
        const int f = 1, t0 = TN - 16;
        if (ln < 8) {
            const int ch = ln >> 2, c4 = ln & 3;
            __builtin_nontemporal_store(*(const f32x4*)&keysT[f][ch][c4 * 4],
                (f32x4*)(out + OFF_KEYS + (long)bb * 2 * TN + ch * TN + t0 + c4 * 4));
        } else if (ln < 24) {
            const int ix = ln - 8, ch = ix >> 2, c4 = ix & 3;
            __builtin_nontemporal_store(*(const f32x4*)&prsT[f][ch][c4 * 4],
                (f32x4*)(out + OFF_PRS + (long)bb * 4 * TN + ch * TN + t0 + c4 * 4));
        } else if (ln < 28) {
            const int c4 = ln - 24;
            __builtin_nontemporal_store(*(const f32x4*)&tmT[f][c4 * 4],
                (f32x4*)(out + OFF_TM + (long)bb * 2 * TN + TN + t0 + c4 * 4));
        }
    }
}

extern "C" void kernel_launch(void* const* d_in, const int* in_sizes, int n_in,
                              void* d_out, int out_size, void* d_ws, size_t ws_size,
                              hipStream_t stream) {
    (void)in_sizes; (void)n_in; (void)out_size; (void)ws_size;
    const float* in    = (const float*)d_in[0];
    const float* w_in  = (const float*)d_in[1];
    const float* b_in  = (const float*)d_in[2];
    const float* w_rec = (const float*)d_in[3];
    const float* b_rec = (const float*)d_in[4];
    const float* w_key = (const float*)d_in[5];
    const float* b_key = (const float*)d_in[6];
    const float* z     = (const float*)d_in[7];
    float* out = (float*)d_out;
    _Float16* whf = (_Float16*)d_ws;     // 512 KB scratch

    hipLaunchKernelGGL(conv_fp16, dim3(HH * HH / 1024), dim3(256), 0, stream, w_rec, whf);
    hipLaunchKernelGGL(rnn_fused, dim3(BB), dim3(NTHR), 0, stream,
                       in, w_in, b_in, b_rec, w_key, b_key, z, out, whf);
}